// Round 11
// baseline (238.345 us; speedup 1.0000x reference)
//
#include <hip/hip_runtime.h>
#include <math.h>

#define NBINS 15

// DPP quad_perm helpers (pure VALU cross-lane within groups of 4 lanes).
template<int CTRL>
__device__ __forceinline__ float dpp_f(float x) {
    return __int_as_float(__builtin_amdgcn_update_dpp(
        0, __float_as_int(x), CTRL, 0xF, 0xF, true));
}
template<int CTRL>
__device__ __forceinline__ int dpp_i(int x) {
    return __builtin_amdgcn_update_dpp(0, x, CTRL, 0xF, 0xF, true);
}
#define QP_XOR1 0xB1   // quad_perm {1,0,3,2}
#define QP_XOR2 0x4E   // quad_perm {2,3,0,1}

// R6 main loop (155.6us, best proven) + fused finalize via last-block ticket
// (epilogue mechanism proven correct across graph replays in R5/R7).
// 4 lanes per row: lane q loads float4-quads {q,4+q,...,20+q} (one contiguous
// 64B segment per row per instruction), online softmax per lane, quad combine
// via 2 DPP steps, balanced tail (lane q handles element 96+q).
__global__ __launch_bounds__(256) void ce_rows100(const float* __restrict__ logits,
                                                  const int* __restrict__ labels,
                                                  float* __restrict__ gbins,
                                                  unsigned int* __restrict__ ticket,
                                                  float* __restrict__ out,
                                                  int N, float inv_n,
                                                  unsigned int nblocks) {
    __shared__ float sb[NBINS * 3];
    __shared__ int slast;
    if (threadIdx.x < NBINS * 3) sb[threadIdx.x] = 0.f;
    if (threadIdx.x == 0) slast = 0;
    __syncthreads();

    const int lane = threadIdx.x & 63;
    const int q = lane & 3;        // lane within quad
    const int rq = lane >> 2;      // row within 16-row chunk
    const int gw = (blockIdx.x * blockDim.x + threadIdx.x) >> 6;
    const int nw = (gridDim.x * blockDim.x) >> 6;
    const int nchunks = (N + 15) >> 4;

    for (int chunk = gw; chunk < nchunks; chunk += nw) {
        const int row = chunk * 16 + rq;
        if (row < N) {
            const float* rpf = logits + (size_t)row * 100;
            const float4* rp = reinterpret_cast<const float4*>(rpf);
            const int lab = labels[row];          // uniform per quad, early issue

            float m = -INFINITY, s = 0.f;
            int arg = 0;
            #pragma unroll
            for (int k = 0; k < 6; ++k) {
                const int qi = 4 * k + q;          // quad index in row, < 24
                float4 v = rp[qi];
                const int bi = qi * 4;
                { float x = v.x; if (x > m) { s *= __expf(m - x); m = x; arg = bi;     } s += __expf(x - m); }
                { float x = v.y; if (x > m) { s *= __expf(m - x); m = x; arg = bi + 1; } s += __expf(x - m); }
                { float x = v.z; if (x > m) { s *= __expf(m - x); m = x; arg = bi + 2; } s += __expf(x - m); }
                { float x = v.w; if (x > m) { s *= __expf(m - x); m = x; arg = bi + 3; } s += __expf(x - m); }
            }
            // balanced tail: lane q handles element 96+q (all lanes active)
            {
                float x = rpf[96 + q];
                if (x > m) { s *= __expf(m - x); m = x; arg = 96 + q; }
                s += __expf(x - m);
            }

            // quad argmax butterfly (first-occurrence: equal max -> smaller index)
            const float ml = m;
            float M = m; int A = arg;
            {
                float t = dpp_f<QP_XOR1>(M); int ti = dpp_i<QP_XOR1>(A);
                if (t > M || (t == M && ti < A)) { M = t; A = ti; }
                t = dpp_f<QP_XOR2>(M); ti = dpp_i<QP_XOR2>(A);
                if (t > M || (t == M && ti < A)) { M = t; A = ti; }
            }
            // quad sum of s_l * exp(m_l - M)
            float sc = s * __expf(ml - M);
            sc += dpp_f<QP_XOR1>(sc);
            sc += dpp_f<QP_XOR2>(sc);

            if (q == 0) {
                const float conf = 1.0f / sc;      // max softmax prob
                int b = (int)ceilf(conf * (float)NBINS) - 1;
                b = min(max(b, 0), NBINS - 1);
                atomicAdd(&sb[b * 3 + 0], 1.0f);
                atomicAdd(&sb[b * 3 + 1], conf);
                if (A == lab) atomicAdd(&sb[b * 3 + 2], 1.0f);
            }
        }
    }

    __syncthreads();
    if (threadIdx.x < NBINS * 3) {
        float v = sb[threadIdx.x];
        if (v != 0.f) atomicAdd(&gbins[threadIdx.x], v);
    }
    __syncthreads();
    if (threadIdx.x == 0) {
        __threadfence();
        unsigned int t = atomicAdd(ticket, 1u);
        if (t == nblocks - 1) slast = 1;
    }
    __syncthreads();
    if (slast && threadIdx.x < 64) {
        __threadfence();
        int t = threadIdx.x;
        float gap = 0.f, w = 0.f;
        bool ne = false;
        if (t < NBINS) {
            // device-scope coherent reads (atomic RMW with 0)
            float c  = atomicAdd(&gbins[t * 3 + 0], 0.f);
            float sc = atomicAdd(&gbins[t * 3 + 1], 0.f);
            float sa = atomicAdd(&gbins[t * 3 + 2], 0.f);
            if (c > 0.f) { ne = true; gap = fabsf(sc / c - sa / c); w = c; }
        }
        float ece = ne ? gap * w * inv_n : 0.f;
        float mce = ne ? gap : -INFINITY;
        #pragma unroll
        for (int off = 1; off < 64; off <<= 1) {
            ece += __shfl_xor(ece, off);
            mce = fmaxf(mce, __shfl_xor(mce, off));
        }
        if (t == 0) {
            out[0] = ece;
            out[1] = (mce == -INFINITY) ? 1.0f : mce;
        }
    }
}

// Generic fallback for C != 100 (scalar per-thread, correct for any C).
__global__ __launch_bounds__(256) void ce_rows_generic(const float* __restrict__ logits,
                                                       const int* __restrict__ labels,
                                                       float* __restrict__ gbins,
                                                       int N, int C) {
    __shared__ float sb[NBINS * 3];
    if (threadIdx.x < NBINS * 3) sb[threadIdx.x] = 0.f;
    __syncthreads();

    const int r = blockIdx.x * blockDim.x + threadIdx.x;
    if (r < N) {
        const float* rp = logits + (size_t)r * (size_t)C;
        float m = -INFINITY, s = 0.f;
        int arg = 0;
        for (int k = 0; k < C; ++k) {
            float x = rp[k];
            if (x > m) { s *= __expf(m - x); m = x; arg = k; }
            s += __expf(x - m);
        }
        float conf = 1.0f / s;
        int b = (int)ceilf(conf * (float)NBINS) - 1;
        b = min(max(b, 0), NBINS - 1);
        atomicAdd(&sb[b * 3 + 0], 1.0f);
        atomicAdd(&sb[b * 3 + 1], conf);
        if (arg == labels[r]) atomicAdd(&sb[b * 3 + 2], 1.0f);
    }
    __syncthreads();
    if (threadIdx.x < NBINS * 3) {
        float v = sb[threadIdx.x];
        if (v != 0.f) atomicAdd(&gbins[threadIdx.x], v);
    }
}

__global__ void ce_final(const float* __restrict__ gbins, float* __restrict__ out,
                         float inv_n) {
    int t = threadIdx.x;
    float gap = 0.f, w = 0.f;
    bool ne = false;
    if (t < NBINS) {
        float c = gbins[t * 3 + 0];
        float sc = gbins[t * 3 + 1];
        float sa = gbins[t * 3 + 2];
        if (c > 0.f) { ne = true; gap = fabsf(sc / c - sa / c); w = c; }
    }
    float ece = ne ? gap * w * inv_n : 0.f;
    float mce = ne ? gap : -INFINITY;
    #pragma unroll
    for (int off = 1; off < 64; off <<= 1) {
        ece += __shfl_xor(ece, off);
        mce = fmaxf(mce, __shfl_xor(mce, off));
    }
    if (t == 0) {
        out[0] = ece;
        out[1] = (mce == -INFINITY) ? 1.0f : mce;
    }
}

extern "C" void kernel_launch(void* const* d_in, const int* in_sizes, int n_in,
                              void* d_out, int out_size, void* d_ws, size_t ws_size,
                              hipStream_t stream) {
    const float* logits = (const float*)d_in[0];
    const int* labels = (const int*)d_in[1];
    int N = in_sizes[1];
    int C = in_sizes[0] / in_sizes[1];   // 100

    float* gbins = (float*)d_ws;
    unsigned int* ticket = (unsigned int*)(gbins + NBINS * 3);

    if (C == 100) {
        (void)hipMemsetAsync(gbins, 0, (NBINS * 3 + 1) * sizeof(float), stream);
        const unsigned int nblocks = 2048;
        ce_rows100<<<nblocks, 256, 0, stream>>>(logits, labels, gbins, ticket,
                                                (float*)d_out, N, 1.0f / (float)N,
                                                nblocks);
    } else {
        (void)hipMemsetAsync(gbins, 0, NBINS * 3 * sizeof(float), stream);
        ce_rows_generic<<<(N + 255) / 256, 256, 0, stream>>>(logits, labels, gbins, N, C);
        ce_final<<<1, 64, 0, stream>>>(gbins, (float*)d_out, 1.0f / (float)N);
    }
}

// Round 12
// 155.337 us; speedup vs baseline: 1.5344x; 1.5344x over previous
//
#include <hip/hip_runtime.h>
#include <math.h>

#define NBINS 15

// DPP quad_perm helpers (pure VALU cross-lane within groups of 4 lanes).
template<int CTRL>
__device__ __forceinline__ float dpp_f(float x) {
    return __int_as_float(__builtin_amdgcn_update_dpp(
        0, __float_as_int(x), CTRL, 0xF, 0xF, true));
}
template<int CTRL>
__device__ __forceinline__ int dpp_i(int x) {
    return __builtin_amdgcn_update_dpp(0, x, CTRL, 0xF, 0xF, true);
}
#define QP_XOR1 0xB1   // quad_perm {1,0,3,2}
#define QP_XOR2 0x4E   // quad_perm {2,3,0,1}

// FINAL (= R6, best of 12 variants at 155.6us).
// 4 lanes per row: lane q loads float4-quads {q,4+q,...,20+q} -> each
// instruction covers one contiguous 64B segment per row (minimal TA work,
// every line fetched once). Online softmax per lane (progressive load consume
// keeps VGPR low, max TLP at 32 waves/CU), quad combine via 2 DPP steps,
// balanced tail (lane q handles element 96+q; uniform exec).
// Measured dead ends: wave-per-row shuffle softmax (DS-pipe bound, 450us);
// thread-per-row (TA-bound, 268us); two-phase all-live ILP & manual pipeline
// (VGPR cliff + fence, 237/247us); nontemporal loads (kill line reuse across
// 400B rows, 191us); LDS-staged linear loads (DS overhead, no BW gain,
// 161us); fused finalize w/ per-block __threadfence (device-fence L2
// writeback storm on non-coherent XCDs, 238us).
__global__ __launch_bounds__(256) void ce_rows100(const float* __restrict__ logits,
                                                  const int* __restrict__ labels,
                                                  float* __restrict__ gbins, int N) {
    __shared__ float sb[NBINS * 3];
    if (threadIdx.x < NBINS * 3) sb[threadIdx.x] = 0.f;
    __syncthreads();

    const int lane = threadIdx.x & 63;
    const int q = lane & 3;        // lane within quad
    const int rq = lane >> 2;      // row within 16-row chunk
    const int gw = (blockIdx.x * blockDim.x + threadIdx.x) >> 6;
    const int nw = (gridDim.x * blockDim.x) >> 6;
    const int nchunks = (N + 15) >> 4;

    for (int chunk = gw; chunk < nchunks; chunk += nw) {
        const int row = chunk * 16 + rq;
        if (row < N) {
            const float* rpf = logits + (size_t)row * 100;
            const float4* rp = reinterpret_cast<const float4*>(rpf);
            const int lab = labels[row];          // uniform per quad, early issue

            float m = -INFINITY, s = 0.f;
            int arg = 0;
            #pragma unroll
            for (int k = 0; k < 6; ++k) {
                const int qi = 4 * k + q;          // quad index in row, < 24
                float4 v = rp[qi];
                const int bi = qi * 4;
                { float x = v.x; if (x > m) { s *= __expf(m - x); m = x; arg = bi;     } s += __expf(x - m); }
                { float x = v.y; if (x > m) { s *= __expf(m - x); m = x; arg = bi + 1; } s += __expf(x - m); }
                { float x = v.z; if (x > m) { s *= __expf(m - x); m = x; arg = bi + 2; } s += __expf(x - m); }
                { float x = v.w; if (x > m) { s *= __expf(m - x); m = x; arg = bi + 3; } s += __expf(x - m); }
            }
            // balanced tail: lane q handles element 96+q (all lanes active)
            {
                float x = rpf[96 + q];
                if (x > m) { s *= __expf(m - x); m = x; arg = 96 + q; }
                s += __expf(x - m);
            }

            // quad argmax butterfly (first-occurrence: equal max -> smaller index)
            const float ml = m;
            float M = m; int A = arg;
            {
                float t = dpp_f<QP_XOR1>(M); int ti = dpp_i<QP_XOR1>(A);
                if (t > M || (t == M && ti < A)) { M = t; A = ti; }
                t = dpp_f<QP_XOR2>(M); ti = dpp_i<QP_XOR2>(A);
                if (t > M || (t == M && ti < A)) { M = t; A = ti; }
            }
            // quad sum of s_l * exp(m_l - M)
            float sc = s * __expf(ml - M);
            sc += dpp_f<QP_XOR1>(sc);
            sc += dpp_f<QP_XOR2>(sc);

            if (q == 0) {
                const float conf = 1.0f / sc;      // max softmax prob
                int b = (int)ceilf(conf * (float)NBINS) - 1;
                b = min(max(b, 0), NBINS - 1);
                atomicAdd(&sb[b * 3 + 0], 1.0f);
                atomicAdd(&sb[b * 3 + 1], conf);
                if (A == lab) atomicAdd(&sb[b * 3 + 2], 1.0f);
            }
        }
    }

    __syncthreads();
    if (threadIdx.x < NBINS * 3) {
        float v = sb[threadIdx.x];
        if (v != 0.f) atomicAdd(&gbins[threadIdx.x], v);
    }
}

// Generic fallback for C != 100 (scalar per-thread, correct for any C).
__global__ __launch_bounds__(256) void ce_rows_generic(const float* __restrict__ logits,
                                                       const int* __restrict__ labels,
                                                       float* __restrict__ gbins,
                                                       int N, int C) {
    __shared__ float sb[NBINS * 3];
    if (threadIdx.x < NBINS * 3) sb[threadIdx.x] = 0.f;
    __syncthreads();

    const int r = blockIdx.x * blockDim.x + threadIdx.x;
    if (r < N) {
        const float* rp = logits + (size_t)r * (size_t)C;
        float m = -INFINITY, s = 0.f;
        int arg = 0;
        for (int k = 0; k < C; ++k) {
            float x = rp[k];
            if (x > m) { s *= __expf(m - x); m = x; arg = k; }
            s += __expf(x - m);
        }
        float conf = 1.0f / s;
        int b = (int)ceilf(conf * (float)NBINS) - 1;
        b = min(max(b, 0), NBINS - 1);
        atomicAdd(&sb[b * 3 + 0], 1.0f);
        atomicAdd(&sb[b * 3 + 1], conf);
        if (arg == labels[r]) atomicAdd(&sb[b * 3 + 2], 1.0f);
    }
    __syncthreads();
    if (threadIdx.x < NBINS * 3) {
        float v = sb[threadIdx.x];
        if (v != 0.f) atomicAdd(&gbins[threadIdx.x], v);
    }
}

__global__ void ce_final(const float* __restrict__ gbins, float* __restrict__ out,
                         float inv_n) {
    int t = threadIdx.x;
    float gap = 0.f, w = 0.f;
    bool ne = false;
    if (t < NBINS) {
        float c = gbins[t * 3 + 0];
        float sc = gbins[t * 3 + 1];
        float sa = gbins[t * 3 + 2];
        if (c > 0.f) { ne = true; gap = fabsf(sc / c - sa / c); w = c; }
    }
    float ece = ne ? gap * w * inv_n : 0.f;
    float mce = ne ? gap : -INFINITY;
    #pragma unroll
    for (int off = 1; off < 64; off <<= 1) {
        ece += __shfl_xor(ece, off);
        mce = fmaxf(mce, __shfl_xor(mce, off));
    }
    if (t == 0) {
        out[0] = ece;
        out[1] = (mce == -INFINITY) ? 1.0f : mce;
    }
}

extern "C" void kernel_launch(void* const* d_in, const int* in_sizes, int n_in,
                              void* d_out, int out_size, void* d_ws, size_t ws_size,
                              hipStream_t stream) {
    const float* logits = (const float*)d_in[0];
    const int* labels = (const int*)d_in[1];
    int N = in_sizes[1];
    int C = in_sizes[0] / in_sizes[1];   // 100

    float* gbins = (float*)d_ws;
    (void)hipMemsetAsync(gbins, 0, NBINS * 3 * sizeof(float), stream);

    if (C == 100) {
        ce_rows100<<<2048, 256, 0, stream>>>(logits, labels, gbins, N);
    } else {
        ce_rows_generic<<<(N + 255) / 256, 256, 0, stream>>>(logits, labels, gbins, N, C);
    }
    ce_final<<<1, 64, 0, stream>>>(gbins, (float*)d_out, 1.0f / (float)N);
}